// Round 2
// baseline (780.903 us; speedup 1.0000x reference)
//
#include <hip/hip_runtime.h>
#include <hip/hip_bf16.h>

#define Bb 8
#define Hh 96
#define Ww 96
#define Dd 768
#define Nn (Hh*Ww)
#define DC 16              // d-chunk
#define NCH (Dd/DC)        // 48
#define SZ 20              // LDS token stride in words (16 data + 4 pad; 5 quads -> coprime with 8 banksets)
#define TMP 0.07f

// ws layout (floats): [0]=align_sum, [1]=pos_sum, [2..9]=sum(w1[b]), [10..17]=sum(w2[b])

__global__ __launch_bounds__(256) void k_wsum(const float* __restrict__ w1,
                                              const float* __restrict__ w2,
                                              float* __restrict__ ws) {
    int j = blockIdx.x;  // 0..15
    const float* src = (j < 8 ? w1 : w2) + (size_t)(j & 7) * Nn;
    float s = 0.f;
    for (int i = threadIdx.x; i < Nn; i += 256) s += src[i];
    for (int off = 32; off > 0; off >>= 1) s += __shfl_down(s, off, 64);
    __shared__ float parts[4];
    int lane = threadIdx.x & 63, wv = threadIdx.x >> 6;
    if (lane == 0) parts[wv] = s;
    __syncthreads();
    if (threadIdx.x == 0) ws[2 + j] = parts[0] + parts[1] + parts[2] + parts[3];
    if (j == 0 && threadIdx.x == 64) ws[0] = 0.f;
    if (j == 0 && threadIdx.x == 65) ws[1] = 0.f;
}

// one block per (b,h); 384 threads = 96 w-columns x 4 d-quarters
__global__ __launch_bounds__(384, 1) void k_main(
    const float* __restrict__ z1, const float* __restrict__ z2,
    const float* __restrict__ w1, const float* __restrict__ w2,
    float* __restrict__ ws) {
    extern __shared__ float sm[];
    float* z1s  = sm;                      // 96*SZ           = 1920
    float* z2s  = z1s + 96*SZ;             // 5*100*SZ        = 10000 (cols padded +2 each side, zeros)
    float* simS = z2s + 5*100*SZ;          // 25*96           = 2400
    float* nrm1 = simS + 25*96;            // 96
    float* nrm2 = nrm1 + 96;               // 5*96            = 480
    float* red  = nrm2 + 480;              // 2
    // total 14898 floats = 59592 B

    const int t = threadIdx.x;
    const int b = blockIdx.x / Hh;
    const int h = blockIdx.x % Hh;
    const int w = t % 96;
    const int quarter = t / 96;            // d-quarter: handles d = quarter*4 .. +3 of each chunk
    const int dq = quarter * 4;

    // zero z2s (padding cols / out-of-image rows stay zero forever) + accumulator arrays
    for (int i = t; i < 5*100*SZ; i += 384) z2s[i] = 0.f;
    for (int i = t; i < 25*96 + 96 + 480 + 2; i += 384) simS[i] = 0.f;   // simS,nrm1,nrm2,red contiguous

    float acc[5][5] = {};     // [rho][delta] raw dot partials
    float nz2[5]    = {};     // z2 sumsq partials (own column, each halo row)
    float nz1       = 0.f;    // z1 sumsq partial

    const size_t zbase = (size_t)b * Nn * Dd;

    for (int c = 0; c < NCH; ++c) {
        const int d0 = c * DC;
        __syncthreads();   // prev-chunk compute done (also orders zero-init on c==0)
        // stage z1 row: 96 tokens x 4 quads = 384 float4 (exactly one per thread)
        {
            int tok = t >> 2, j = t & 3;
            float4 v = *(const float4*)(z1 + zbase + (size_t)(h*Ww + tok)*Dd + d0 + j*4);
            *(float4*)&z1s[tok*SZ + j*4] = v;
        }
        // stage z2 halo rows: 5 x 96 x 4 = 1920 float4 -> 5 per thread
        #pragma unroll
        for (int rep = 0; rep < 5; ++rep) {
            int idx = t + rep*384;       // 0..1919
            int rho = idx / 384;         // == rep (t < 384)
            int rem = idx - rho*384;
            int tok = rem >> 2, j = rem & 3;
            int hr  = h + 2 - rho;       // image row for shift dy = rho-2
            if (hr >= 0 && hr < Hh) {
                float4 v = *(const float4*)(z2 + zbase + (size_t)(hr*Ww + tok)*Dd + d0 + j*4);
                *(float4*)&z2s[(rho*100 + tok + 2)*SZ + j*4] = v;
            }
        }
        __syncthreads();
        // compute: this thread's 4 d's
        const float4 a = *(const float4*)&z1s[w*SZ + dq];
        nz1 += a.x*a.x + a.y*a.y + a.z*a.z + a.w*a.w;
        #pragma unroll
        for (int rho = 0; rho < 5; ++rho) {
            const float* rowp = &z2s[(rho*100 + w)*SZ + dq];   // LDS col w = image col w-2
            #pragma unroll
            for (int k = 0; k < 5; ++k) {                      // image col w+k-2, delta = 4-k
                const float4 q = *(const float4*)(rowp + k*SZ);
                acc[rho][4-k] += a.x*q.x + a.y*q.y + a.z*q.z + a.w*q.w;
                if (k == 2) nz2[rho] += q.x*q.x + q.y*q.y + q.z*q.z + q.w*q.w;
            }
        }
    }

    // combine d-quarter partials
    atomicAdd(&nrm1[w], nz1);
    #pragma unroll
    for (int rho = 0; rho < 5; ++rho) atomicAdd(&nrm2[rho*96 + w], nz2[rho]);
    #pragma unroll
    for (int rho = 0; rho < 5; ++rho)
        #pragma unroll
        for (int del = 0; del < 5; ++del)
            atomicAdd(&simS[(rho*5 + del)*96 + w], acc[rho][del]);
    __syncthreads();

    if (t < 96) {
        const float inv1 = 1.f / fmaxf(sqrtf(nrm1[t]), 1e-12f);
        float sims[25];
        #pragma unroll
        for (int s = 0; s < 25; ++s) {
            int rho = s / 5, del = s % 5;
            int col = t + 2 - del;                 // image col of the z2 token
            float v = simS[s*96 + t];
            float iv2 = 0.f;
            if (col >= 0 && col < 96) iv2 = 1.f / fmaxf(sqrtf(nrm2[rho*96 + col]), 1e-12f);
            sims[s] = v * inv1 * iv2;              // out-of-image -> v==0 -> sim 0, matches zero-pad
        }
        float m = -1e30f;
        #pragma unroll
        for (int s = 0; s < 25; ++s) m = fmaxf(m, sims[s]);
        float den = 0.f, num = 0.f;
        #pragma unroll
        for (int s = 0; s < 25; ++s) {
            float p = __expf((sims[s] - m) * (1.f / TMP));
            den += p; num += p * sims[s];
        }
        float ssb = num / den;
        int base = b*Nn + h*Ww + t;
        float wa = 0.5f * (w1[base] / (ws[2 + b] + 1e-10f) + w2[base] / (ws[10 + b] + 1e-10f));
        atomicAdd(&red[0], (1.f - ssb) * wa);
        atomicAdd(&red[1], ssb);
    }
    __syncthreads();
    if (t == 0) {
        atomicAdd(&ws[0], red[0]);
        atomicAdd(&ws[1], red[1]);
    }
}

__global__ void k_final(const float* __restrict__ ws, float* __restrict__ out) {
    if (threadIdx.x == 0) {
        out[0] = ws[0] / (float)Bb;
        out[1] = ws[1] / (float)(Bb * Nn);
    }
}

extern "C" void kernel_launch(void* const* d_in, const int* in_sizes, int n_in,
                              void* d_out, int out_size, void* d_ws, size_t ws_size,
                              hipStream_t stream) {
    const float* z1 = (const float*)d_in[0];
    const float* z2 = (const float*)d_in[1];
    const float* w1 = (const float*)d_in[2];
    const float* w2 = (const float*)d_in[3];
    float* ws = (float*)d_ws;
    float* out = (float*)d_out;

    k_wsum<<<16, 256, 0, stream>>>(w1, w2, ws);
    size_t smbytes = (size_t)(96*SZ + 5*100*SZ + 25*96 + 96 + 480 + 2) * sizeof(float);
    k_main<<<Bb*Hh, 384, smbytes, stream>>>(z1, z2, w1, w2, ws);
    k_final<<<1, 64, 0, stream>>>(ws, out);
}